// Round 14
// baseline (399.351 us; speedup 1.0000x reference)
//
#include <hip/hip_runtime.h>
#include <hip/hip_bf16.h>
#include <hip/hip_cooperative_groups.h>
#include <math.h>

namespace cg = cooperative_groups;

typedef __bf16 bf16_t;
typedef __bf16 bf16x8 __attribute__((ext_vector_type(8)));
typedef __bf16 bf16x4 __attribute__((ext_vector_type(4)));
typedef float  f32x4  __attribute__((ext_vector_type(4)));

#define NBATCH 4
#define SB     4096
#define BS     (NBATCH*SB)   // 16384 total rows
#define DIM    256

// ---------------- helpers ----------------

__device__ __forceinline__ float softplus_f(float x) {
  return fmaxf(x, 0.0f) + log1pf(__expf(-fabsf(x)));
}

__device__ __forceinline__ void gload_lds16(const void* g, void* l) {
  __builtin_amdgcn_global_load_lds(
      (const __attribute__((address_space(1))) void*)g,
      (__attribute__((address_space(3))) void*)l,
      16, 0, 0);
}

__device__ __forceinline__ void cvt4(const float* __restrict__ s,
                                     bf16_t* __restrict__ d, int qi) {
  const float4 v = *(const float4*)(s + (size_t)qi * 4);
  bf16x4 o;
  o[0] = (bf16_t)v.x; o[1] = (bf16_t)v.y; o[2] = (bf16_t)v.z; o[3] = (bf16_t)v.w;
  *(bf16x4*)(d + (size_t)qi * 4) = o;
}

// ---------------- R3-measured 128x128 staged-GEMM core ----------------
// C(128x128) = A[r0.., 0:256] * B[c0.., 0:256]^T, both bf16 row-major
// (row stride 512B). 4 waves 2x2; XOR-swizzled LDS (pre-swizzled global src
// for global_load_lds; swizzled ds_read_b128 at use).
__device__ __forceinline__ void gemm128_core(
    const bf16_t* __restrict__ Abase,
    const bf16_t* __restrict__ Bbase,
    char* smem, int tid, f32x4 acc[4][4]) {
  const int lane = tid & 63;
  const int w = tid >> 6;
  const int wr = w & 1, wc = w >> 1;
  #pragma unroll
  for (int kk = 0; kk < 2; ++kk) {
    const char* asrc = (const char*)Abase + kk * 256;
    const char* bsrc = (const char*)Bbase + kk * 256;
    #pragma unroll
    for (int it = 0; it < 8; ++it) {
      const int L = it * 256 + tid;
      const int row = L >> 4;
      const int lch = (L & 15) ^ (row & 7);
      char* la = smem + (size_t)(it * 256 + w * 64) * 16;
      char* lb = la + 32768;
      gload_lds16(asrc + (size_t)row * 512 + lch * 16, la);
      gload_lds16(bsrc + (size_t)row * 512 + lch * 16, lb);
    }
    __syncthreads();
    #pragma unroll
    for (int ks = 0; ks < 4; ++ks) {
      const int kb = ks * 64 + ((lane >> 4) << 4);
      bf16x8 af[4], bg[4];
      #pragma unroll
      for (int mi = 0; mi < 4; ++mi) {
        const int row = wr * 64 + mi * 16 + (lane & 15);
        const int ch = (kb >> 4) ^ (row & 7);
        af[mi] = *(const bf16x8*)(smem + (size_t)row * 256 + ch * 16);
      }
      #pragma unroll
      for (int ni = 0; ni < 4; ++ni) {
        const int row = wc * 64 + ni * 16 + (lane & 15);
        const int ch = (kb >> 4) ^ (row & 7);
        bg[ni] = *(const bf16x8*)(smem + 32768 + (size_t)row * 256 + ch * 16);
      }
      #pragma unroll
      for (int mi = 0; mi < 4; ++mi)
        #pragma unroll
        for (int ni = 0; ni < 4; ++ni)
          acc[mi][ni] = __builtin_amdgcn_mfma_f32_16x16x32_bf16(
              af[mi], bg[ni], acc[mi][ni], 0, 0, 0);
    }
    __syncthreads();
  }
}

// ---------------- stage unit bodies ----------------

__device__ __forceinline__ void qkv_unit(
    int mode, int r0, int c0, int tid, char* smem,
    const bf16_t* __restrict__ xb,
    const bf16_t* __restrict__ Wqb, const bf16_t* __restrict__ Wkb,
    const bf16_t* __restrict__ Wvob,
    const float* __restrict__ bq, const float* __restrict__ bk,
    const float* __restrict__ bvo,
    bf16_t* __restrict__ qo, bf16_t* __restrict__ kT,
    bf16_t* __restrict__ vT) {
  const bf16_t* W   = (mode == 0) ? Wqb : (mode == 1) ? Wkb : Wvob;
  const float* bias = (mode == 0) ? bq  : (mode == 1) ? bk  : bvo;
  const int lane = tid & 63;
  const int w = tid >> 6;
  const int wr = w & 1, wc = w >> 1;

  f32x4 zero = {0.0f, 0.0f, 0.0f, 0.0f};
  f32x4 acc[4][4];
  #pragma unroll
  for (int i = 0; i < 4; ++i)
    #pragma unroll
    for (int j = 0; j < 4; ++j) acc[i][j] = zero;

  gemm128_core(xb + (size_t)r0 * DIM, W + (size_t)c0 * DIM, smem, tid, acc);

  const int batch = r0 >> 12;
  #pragma unroll
  for (int ni = 0; ni < 4; ++ni) {
    const int col = c0 + wc * 64 + ni * 16 + (lane & 15);
    const float bb = bias[col];
    #pragma unroll
    for (int mi = 0; mi < 4; ++mi) {
      const int srow = r0 + wr * 64 + mi * 16 + ((lane >> 4) << 2);
      f32x4 v = acc[mi][ni];
      float o0 = v[0] + bb, o1 = v[1] + bb, o2 = v[2] + bb, o3 = v[3] + bb;
      if (mode < 2) {
        o0 = softplus_f(o0); o1 = softplus_f(o1);
        o2 = softplus_f(o2); o3 = softplus_f(o3);
      }
      if (mode == 0) {
        qo[(size_t)(srow + 0) * DIM + col] = (bf16_t)o0;
        qo[(size_t)(srow + 1) * DIM + col] = (bf16_t)o1;
        qo[(size_t)(srow + 2) * DIM + col] = (bf16_t)o2;
        qo[(size_t)(srow + 3) * DIM + col] = (bf16_t)o3;
      } else {
        bf16_t* dst = (mode == 1) ? kT : vT;
        const int sin = srow & (SB - 1);
        bf16x4 p;
        p[0] = (bf16_t)o0; p[1] = (bf16_t)o1; p[2] = (bf16_t)o2; p[3] = (bf16_t)o3;
        *(bf16x4*)(dst + (size_t)batch * DIM * SB + (size_t)col * SB + sin) = p;
      }
    }
  }
}

// M partial over one s-chunk: MTp[(sc*NBATCH+b)] += v'[s][j]*k[s][d]
__device__ __forceinline__ void m_unit(
    int quad, int sc, int b, int tid, int iters, int chunk_elems,
    const bf16_t* __restrict__ kT, const bf16_t* __restrict__ vT,
    float* __restrict__ MTp) {
  const int lane = tid & 63;
  const int w = tid >> 6;
  const int wr = w & 1, wc = w >> 1;
  const int j0 = (quad & 1) * 128 + wr * 64;
  const int d0 = (quad >> 1) * 128 + wc * 64;
  const bf16_t* vb = vT + (size_t)b * DIM * SB;
  const bf16_t* kb = kT + (size_t)b * DIM * SB;

  f32x4 zero = {0.0f, 0.0f, 0.0f, 0.0f};
  f32x4 acc[4][4];
  #pragma unroll
  for (int i = 0; i < 4; ++i)
    #pragma unroll
    for (int j = 0; j < 4; ++j) acc[i][j] = zero;

  const int svec = sc * chunk_elems + ((lane >> 4) << 3);
  for (int it = 0; it < iters; ++it) {
    const int s = svec + it * 32;
    bf16x8 af[4], bg[4];
    #pragma unroll
    for (int mi = 0; mi < 4; ++mi)
      af[mi] = *(const bf16x8*)(vb + (size_t)(j0 + mi * 16 + (lane & 15)) * SB + s);
    #pragma unroll
    for (int ni = 0; ni < 4; ++ni)
      bg[ni] = *(const bf16x8*)(kb + (size_t)(d0 + ni * 16 + (lane & 15)) * SB + s);
    #pragma unroll
    for (int mi = 0; mi < 4; ++mi)
      #pragma unroll
      for (int ni = 0; ni < 4; ++ni)
        acc[mi][ni] = __builtin_amdgcn_mfma_f32_16x16x32_bf16(
            af[mi], bg[ni], acc[mi][ni], 0, 0, 0);
  }

  float* o = MTp + ((size_t)sc * NBATCH + b) * DIM * DIM;
  #pragma unroll
  for (int mi = 0; mi < 4; ++mi) {
    const int row = j0 + mi * 16 + ((lane >> 4) << 2);
    #pragma unroll
    for (int ni = 0; ni < 4; ++ni) {
      const int col = d0 + ni * 16 + (lane & 15);
      #pragma unroll
      for (int r = 0; r < 4; ++r)
        o[(size_t)(row + r) * DIM + col] = acc[mi][ni][r];
    }
  }
}

__device__ __forceinline__ void reduce_fn(int qi, int n,
                                          const float* __restrict__ MTp,
                                          bf16_t* __restrict__ NTb) {
  f32x4 s = {0.0f, 0.0f, 0.0f, 0.0f};
  for (int c = 0; c < n; ++c) {
    const float4 v =
        *(const float4*)(MTp + (size_t)c * NBATCH * DIM * DIM + (size_t)qi * 4);
    s[0] += v.x; s[1] += v.y; s[2] += v.z; s[3] += v.w;
  }
  bf16x4 o;
  o[0] = (bf16_t)s[0]; o[1] = (bf16_t)s[1];
  o[2] = (bf16_t)s[2]; o[3] = (bf16_t)s[3];
  *(bf16x4*)(NTb + (size_t)qi * 4) = o;
}

__device__ __forceinline__ void out_unit(
    int r0, int c0, int tid, char* smem,
    const bf16_t* __restrict__ qo, const bf16_t* __restrict__ NTb,
    const float* __restrict__ bo, float* __restrict__ out) {
  const int batch = r0 >> 12;
  const int lane = tid & 63;
  const int w = tid >> 6;
  const int wr = w & 1, wc = w >> 1;

  f32x4 zero = {0.0f, 0.0f, 0.0f, 0.0f};
  f32x4 acc[4][4];
  #pragma unroll
  for (int i = 0; i < 4; ++i)
    #pragma unroll
    for (int j = 0; j < 4; ++j) acc[i][j] = zero;

  gemm128_core(qo + (size_t)r0 * DIM,
               NTb + (size_t)batch * DIM * DIM + (size_t)c0 * DIM,
               smem, tid, acc);

  #pragma unroll
  for (int ni = 0; ni < 4; ++ni) {
    const int col = c0 + wc * 64 + ni * 16 + (lane & 15);
    const float bb = bo[col];
    #pragma unroll
    for (int mi = 0; mi < 4; ++mi) {
      const int srow = r0 + wr * 64 + mi * 16 + ((lane >> 4) << 2);
      f32x4 v = acc[mi][ni];
      #pragma unroll
      for (int r = 0; r < 4; ++r)
        out[(size_t)(srow + r) * DIM + col] = v[r] + bb;
    }
  }
}

// ---------------- mega kernel (cooperative, 512 blocks x 256 thr) --------
__global__ __launch_bounds__(256) void mega_kernel(
    const float* __restrict__ x,  const float* __restrict__ Wq,
    const float* __restrict__ bq, const float* __restrict__ Wk,
    const float* __restrict__ bk, const float* __restrict__ Wv,
    const float* __restrict__ bv, const float* __restrict__ Wo,
    const float* __restrict__ bo, float* __restrict__ out,
    bf16_t* __restrict__ xb,  bf16_t* __restrict__ qo,
    bf16_t* __restrict__ kT,  bf16_t* __restrict__ vT,
    bf16_t* __restrict__ Wqb, bf16_t* __restrict__ Wkb,
    bf16_t* __restrict__ Wvob, float* __restrict__ bvo,
    bf16_t* __restrict__ NTb, float* __restrict__ MTp) {
  cg::grid_group grid = cg::this_grid();
  __shared__ __align__(16) char smem[65536];
  const int bid = blockIdx.x;   // 0..511
  const int tid = threadIdx.x;  // 0..255

  // ---- S0: x/W -> bf16 (blocks 0..255) || Wvo = Wo@Wv fold (256..511)
  if (bid < 256) {
    const int QX = BS * DIM / 4, QW = DIM * DIM / 4;
    for (int qi = bid * 256 + tid; qi < QX + 2 * QW; qi += 256 * 256) {
      if (qi < QX)           cvt4(x,  xb,  qi);
      else if (qi < QX + QW) cvt4(Wq, Wqb, qi - QX);
      else                   cvt4(Wk, Wkb, qi - QX - QW);
    }
  } else {
    const int j = bid - 256, t = tid;
    float a = 0.0f;
    for (int i = 0; i < DIM; ++i)
      a = fmaf(Wo[j * DIM + i], Wv[i * DIM + t], a);
    Wvob[(size_t)j * DIM + t] = (bf16_t)a;
    if (t == 0) {
      float s = 0.0f;
      for (int i = 0; i < DIM; ++i) s = fmaf(Wo[j * DIM + i], bv[i], s);
      bvo[j] = s;
    }
  }
  grid.sync();

  // ---- S1: qkv projections, 768 units (128 rowtiles x 2 colhalves x 3)
  for (int u = bid; u < 768; u += 512) {
    const int mode = u >> 8;
    const int rest = u & 255;
    qkv_unit(mode, (rest >> 1) * 128, (rest & 1) * 128, tid, smem,
             xb, Wqb, Wkb, Wvob, bq, bk, bvo, qo, kT, vT);
  }
  grid.sync();

  // ---- S2: M partials, 512 units = 4 quad x 32 sc(128) x 4 batch
  m_unit(bid >> 7, (bid >> 2) & 31, bid & 3, tid, 4, 128, kT, vT, MTp);
  grid.sync();

  // ---- S3: reduce 32 partials -> bf16 NTb
  {
    const int qi = bid * 256 + tid;
    if (qi < NBATCH * DIM * DIM / 4) reduce_fn(qi, 32, MTp, NTb);
  }
  grid.sync();

  // ---- S4: out = q @ NB^T + bo, 256 units
  if (bid < 256)
    out_unit((bid >> 1) * 128, (bid & 1) * 128, tid, smem, qo, NTb, bo, out);
}

// ---------------- fallback (R3-measured 5-kernel chain) ----------------

__global__ void prep_fb(const float* __restrict__ x,
                        const float* __restrict__ Wq,
                        const float* __restrict__ Wk,
                        const float* __restrict__ Wv,
                        const float* __restrict__ Wo,
                        const float* __restrict__ bv,
                        bf16_t* __restrict__ xb, bf16_t* __restrict__ Wqb,
                        bf16_t* __restrict__ Wkb, bf16_t* __restrict__ Wvob,
                        float* __restrict__ bvo) {
  if (blockIdx.x < 1024) {
    const int QX = BS * DIM / 4, QW = DIM * DIM / 4;
    for (int qi = blockIdx.x * blockDim.x + threadIdx.x; qi < QX + 2 * QW;
         qi += 1024 * blockDim.x) {
      if (qi < QX)           cvt4(x,  xb,  qi);
      else if (qi < QX + QW) cvt4(Wq, Wqb, qi - QX);
      else                   cvt4(Wk, Wkb, qi - QX - QW);
    }
  } else {
    const int j = blockIdx.x - 1024, t = threadIdx.x;
    float a = 0.0f;
    for (int i = 0; i < DIM; ++i)
      a = fmaf(Wo[j * DIM + i], Wv[i * DIM + t], a);
    Wvob[(size_t)j * DIM + t] = (bf16_t)a;
    if (t == 0) {
      float s = 0.0f;
      for (int i = 0; i < DIM; ++i) s = fmaf(Wo[j * DIM + i], bv[i], s);
      bvo[j] = s;
    }
  }
}

__global__ __launch_bounds__(256) void qkv_fb(
    const bf16_t* __restrict__ xb, const bf16_t* __restrict__ Wqb,
    const bf16_t* __restrict__ Wkb, const bf16_t* __restrict__ Wvob,
    const float* __restrict__ bq, const float* __restrict__ bk,
    const float* __restrict__ bvo, bf16_t* __restrict__ qo,
    bf16_t* __restrict__ kT, bf16_t* __restrict__ vT) {
  __shared__ __align__(16) char smem[65536];
  qkv_unit(blockIdx.z, blockIdx.x * 128, blockIdx.y * 128, threadIdx.x, smem,
           xb, Wqb, Wkb, Wvob, bq, bk, bvo, qo, kT, vT);
}

__global__ __launch_bounds__(256) void m_fb(const bf16_t* __restrict__ kT,
                                            const bf16_t* __restrict__ vT,
                                            float* __restrict__ MTp) {
  m_unit(blockIdx.x, blockIdx.y, blockIdx.z, threadIdx.x, 8, 256, kT, vT, MTp);
}

__global__ void reduce_fb(const float* __restrict__ MTp,
                          bf16_t* __restrict__ NTb) {
  reduce_fn(blockIdx.x * blockDim.x + threadIdx.x, 16, MTp, NTb);
}

__global__ __launch_bounds__(256) void out_fb(
    const bf16_t* __restrict__ qo, const bf16_t* __restrict__ NTb,
    const float* __restrict__ bo, float* __restrict__ out) {
  __shared__ __align__(16) char smem[65536];
  out_unit(blockIdx.x * 128, blockIdx.y * 128, threadIdx.x, smem,
           qo, NTb, bo, out);
}

// ---------------- launch ----------------

extern "C" void kernel_launch(void* const* d_in, const int* in_sizes, int n_in,
                              void* d_out, int out_size, void* d_ws, size_t ws_size,
                              hipStream_t stream) {
  const float* x  = (const float*)d_in[0];
  const float* Wq = (const float*)d_in[1];
  const float* bq = (const float*)d_in[2];
  const float* Wk = (const float*)d_in[3];
  const float* bk = (const float*)d_in[4];
  const float* Wv = (const float*)d_in[5];
  const float* bv = (const float*)d_in[6];
  const float* Wo = (const float*)d_in[7];
  const float* bo = (const float*)d_in[8];
  float* out = (float*)d_out;

  char* ws = (char*)d_ws;
  bf16_t* xb   = (bf16_t*)(ws);                 //  8,388,608 B
  bf16_t* qo   = (bf16_t*)(ws + 8388608);       //  8,388,608 B
  bf16_t* kT   = (bf16_t*)(ws + 16777216);      //  8,388,608 B
  bf16_t* vT   = (bf16_t*)(ws + 25165824);      //  8,388,608 B
  bf16_t* Wqb  = (bf16_t*)(ws + 33554432);      //    131,072 B
  bf16_t* Wkb  = (bf16_t*)(ws + 33685504);      //    131,072 B
  bf16_t* Wvob = (bf16_t*)(ws + 33816576);      //    131,072 B
  float*  bvo  = (float*)(ws + 33947648);       //      1,024 B
  bf16_t* NTb  = (bf16_t*)(ws + 33948672);      //    524,288 B
  float*  MTp  = (float*)(ws + 34472960);       // 33,554,432 B (end ~68MB)

  int dev = 0, coop = 0;
  hipGetDevice(&dev);
  hipDeviceGetAttribute(&coop, hipDeviceAttributeCooperativeLaunch, dev);

  bool done = false;
  if (coop) {
    void* args[] = {(void*)&x,  (void*)&Wq, (void*)&bq, (void*)&Wk,
                    (void*)&bk, (void*)&Wv, (void*)&bv, (void*)&Wo,
                    (void*)&bo, (void*)&out,
                    (void*)&xb, (void*)&qo, (void*)&kT, (void*)&vT,
                    (void*)&Wqb, (void*)&Wkb, (void*)&Wvob, (void*)&bvo,
                    (void*)&NTb, (void*)&MTp};
    hipError_t e = hipLaunchCooperativeKernel((const void*)mega_kernel,
                                              dim3(512), dim3(256),
                                              args, 0, stream);
    done = (e == hipSuccess);
  }
  if (!done) {
    prep_fb<<<1280, 256, 0, stream>>>(x, Wq, Wk, Wv, Wo, bv,
                                      xb, Wqb, Wkb, Wvob, bvo);
    qkv_fb<<<dim3(128, 2, 3), 256, 0, stream>>>(xb, Wqb, Wkb, Wvob,
                                                bq, bk, bvo, qo, kT, vT);
    m_fb<<<dim3(4, 16, 4), 256, 0, stream>>>(kT, vT, MTp);
    reduce_fb<<<256, 256, 0, stream>>>(MTp, NTb);
    out_fb<<<dim3(128, 2), 256, 0, stream>>>(qo, NTb, bo, out);
  }
}